// Round 1
// baseline (250.840 us; speedup 1.0000x reference)
//
#include <hip/hip_runtime.h>
#include <hip/hip_bf16.h>

// LinearShift forward:
//   out = q16(input) @ (exp2(round(shift))*sign(sign)).T + q16(bias)
// Strategy: quantize input -> bf16, build power-of-two weights -> bf16 (exact),
// then bf16 MFMA GEMM (m97-structure: 128x128 tile, BK=32, global_load_lds w=16).
// Workspace layout: [A_bf16: M*K] [W_bf16: N*K]  (needs 67.2 MB of d_ws)

#define BM 128
#define BN 128
#define BK 32

typedef __bf16 bf16_t;
typedef __attribute__((ext_vector_type(8))) __bf16 bf16x8;
typedef __attribute__((ext_vector_type(4))) __bf16 bf16x4;
typedef __attribute__((ext_vector_type(4))) float f32x4;

__device__ __forceinline__ float q16(float x) {
    // floor-quantize to 2^-16 steps, clamp to [-2^15, 2^15 - 1]
    float f = floorf(x * 65536.0f) * (1.0f / 65536.0f);
    return fminf(fmaxf(f, -32768.0f), 32767.0f);
}

__global__ void quant_input_kernel(const float* __restrict__ in,
                                   bf16_t* __restrict__ out, int nvec) {
    int stride = gridDim.x * blockDim.x;
    for (int i = blockIdx.x * blockDim.x + threadIdx.x; i < nvec; i += stride) {
        float4 v = reinterpret_cast<const float4*>(in)[i];
        bf16x4 o;
        o[0] = (bf16_t)q16(v.x);
        o[1] = (bf16_t)q16(v.y);
        o[2] = (bf16_t)q16(v.z);
        o[3] = (bf16_t)q16(v.w);
        reinterpret_cast<bf16x4*>(out)[i] = o;
    }
}

__global__ void make_weight_kernel(const float* __restrict__ shift,
                                   const float* __restrict__ sign_,
                                   bf16_t* __restrict__ out, int nvec) {
    int stride = gridDim.x * blockDim.x;
    for (int i = blockIdx.x * blockDim.x + threadIdx.x; i < nvec; i += stride) {
        float4 sh = reinterpret_cast<const float4*>(shift)[i];
        float4 sg = reinterpret_cast<const float4*>(sign_)[i];
        float shs[4] = {sh.x, sh.y, sh.z, sh.w};
        float sgs[4] = {sg.x, sg.y, sg.z, sg.w};
        bf16x4 o;
#pragma unroll
        for (int j = 0; j < 4; ++j) {
            float s = fminf(fmaxf(sgs[j], -1.0f), 1.0f);
            float sv = (s > 0.0f) ? 1.0f : ((s < 0.0f) ? -1.0f : 0.0f);
            // rintf = round-half-even, matches jnp.round; exp2f exact on integers
            o[j] = (bf16_t)(exp2f(rintf(shs[j])) * sv);
        }
        reinterpret_cast<bf16x4*>(out)[i] = o;
    }
}

// C[M][N] = A[M][K] * B[N][K]^T + q16(bias)[N]
// m97 structure: 4 waves, each computes a 64x64 quadrant as 4x4 frags of 16x16.
__global__ __launch_bounds__(256)
void gemm_bt_bias_kernel(const bf16_t* __restrict__ A,
                         const bf16_t* __restrict__ B,
                         const float* __restrict__ bias,
                         float* __restrict__ C,
                         int M, int N, int K) {
    __shared__ __align__(16) bf16_t As[BM * BK];  // 8 KB
    __shared__ __align__(16) bf16_t Bs[BN * BK];  // 8 KB

    const int ntn = N / BN;
    const int tile_m = (blockIdx.x / ntn) * BM;
    const int tile_n = (blockIdx.x % ntn) * BN;

    const int tid = threadIdx.x;
    const int wid = tid >> 6;
    const int lane = tid & 63;

    const int wave_m = (wid >> 1) * 64;
    const int wave_n = (wid & 1) * 64;

    // staging: chunk c = 16 rows of a tile; wave w loads chunks w and w+4 of A and B.
    // global_load_lds writes LDS at uniform base + lane*16B (linear), so the
    // per-lane global address must match that order: row = lane/4, kq = lane%4.
    const int r_in_chunk = lane >> 2;
    const int kq = (lane & 3) * 8;
    const int c0 = wid;
    const int c1 = wid + 4;

    const bf16_t* gA0 = A + (size_t)(tile_m + c0 * 16 + r_in_chunk) * K + kq;
    const bf16_t* gA1 = A + (size_t)(tile_m + c1 * 16 + r_in_chunk) * K + kq;
    const bf16_t* gB0 = B + (size_t)(tile_n + c0 * 16 + r_in_chunk) * K + kq;
    const bf16_t* gB1 = B + (size_t)(tile_n + c1 * 16 + r_in_chunk) * K + kq;

    bf16_t* lA0 = As + c0 * 16 * BK;
    bf16_t* lA1 = As + c1 * 16 * BK;
    bf16_t* lB0 = Bs + c0 * 16 * BK;
    bf16_t* lB1 = Bs + c1 * 16 * BK;

    f32x4 acc[4][4] = {};

    // fragment read coords (A: row=lane&15, k0=(lane>>4)*8; B^T same by symmetry)
    const int frow = lane & 15;
    const int fk = (lane >> 4) * 8;

    for (int kt = 0; kt < K; kt += BK) {
        __syncthreads();  // previous tile's ds_reads done before overwrite
        __builtin_amdgcn_global_load_lds(
            (const __attribute__((address_space(1))) void*)(gA0 + kt),
            (__attribute__((address_space(3))) void*)lA0, 16, 0, 0);
        __builtin_amdgcn_global_load_lds(
            (const __attribute__((address_space(1))) void*)(gA1 + kt),
            (__attribute__((address_space(3))) void*)lA1, 16, 0, 0);
        __builtin_amdgcn_global_load_lds(
            (const __attribute__((address_space(1))) void*)(gB0 + kt),
            (__attribute__((address_space(3))) void*)lB0, 16, 0, 0);
        __builtin_amdgcn_global_load_lds(
            (const __attribute__((address_space(1))) void*)(gB1 + kt),
            (__attribute__((address_space(3))) void*)lB1, 16, 0, 0);
        __syncthreads();  // compiler emits vmcnt(0) drain before barrier

        bf16x8 a_frag[4], b_frag[4];
#pragma unroll
        for (int i = 0; i < 4; ++i) {
            a_frag[i] = *reinterpret_cast<const bf16x8*>(
                &As[(wave_m + i * 16 + frow) * BK + fk]);
            b_frag[i] = *reinterpret_cast<const bf16x8*>(
                &Bs[(wave_n + i * 16 + frow) * BK + fk]);
        }
#pragma unroll
        for (int i = 0; i < 4; ++i)
#pragma unroll
            for (int j = 0; j < 4; ++j)
                acc[i][j] = __builtin_amdgcn_mfma_f32_16x16x32_bf16(
                    a_frag[i], b_frag[j], acc[i][j], 0, 0, 0);
    }

    // epilogue: C/D layout for 16x16x32 bf16: col=lane&15, row=(lane>>4)*4+reg
    const int ccol = lane & 15;
    const int crow4 = (lane >> 4) * 4;
#pragma unroll
    for (int j = 0; j < 4; ++j) {
        const int gcol = tile_n + wave_n + j * 16 + ccol;
        const float qb = q16(bias[gcol]);
#pragma unroll
        for (int i = 0; i < 4; ++i) {
            const int grow0 = tile_m + wave_m + i * 16 + crow4;
#pragma unroll
            for (int r = 0; r < 4; ++r) {
                C[(size_t)(grow0 + r) * N + gcol] = acc[i][j][r] + qb;
            }
        }
    }
}

extern "C" void kernel_launch(void* const* d_in, const int* in_sizes, int n_in,
                              void* d_out, int out_size, void* d_ws, size_t ws_size,
                              hipStream_t stream) {
    const float* inp   = (const float*)d_in[0];
    const float* shift = (const float*)d_in[1];
    const float* sign_ = (const float*)d_in[2];
    const float* bias  = (const float*)d_in[3];
    float* out = (float*)d_out;

    const int OUT_F = in_sizes[3];              // 4096
    const int IN_F  = in_sizes[1] / OUT_F;      // 4096
    const int Mrows = in_sizes[0] / IN_F;       // 4096

    bf16_t* Aq = (bf16_t*)d_ws;
    bf16_t* Wq = Aq + (size_t)Mrows * IN_F;     // needs (M*K + N*K)*2 = 67.2 MB ws

    const int nA = Mrows * IN_F;
    const int nW = OUT_F * IN_F;

    quant_input_kernel<<<2048, 256, 0, stream>>>(inp, Aq, nA >> 2);
    make_weight_kernel<<<2048, 256, 0, stream>>>(shift, sign_, Wq, nW >> 2);

    dim3 grid((Mrows / BM) * (OUT_F / BN));
    gemm_bt_bias_kernel<<<grid, 256, 0, stream>>>(Aq, Wq, bias, out,
                                                  Mrows, OUT_F, IN_F);
}

// Round 2
// 162.291 us; speedup vs baseline: 1.5456x; 1.5456x over previous
//
#include <hip/hip_runtime.h>
#include <hip/hip_bf16.h>

// LinearShift forward:
//   out = q16(input) @ (exp2(round(shift))*sign(sign)).T + q16(bias)
// bf16 MFMA GEMM, 256x256 tile, BK=64, 8-phase schedule (T2+T3+T4+T5):
//  - 8 waves (2Mx4N), 512 threads, 128 KiB LDS double-buffered half-tiles
//  - global_load_lds w=16, linear LDS dest + inverse-swizzled global source
//  - 3-bit XOR swizzle (byte bits 4-6 ^= row bits 0-2) kills ds_read conflicts
//  - counted s_waitcnt vmcnt(4) once per K-tile (never 0 in main loop)
//  - s_setprio(1) around MFMA clusters, bijective XCD blockIdx swizzle

#define BM 256
#define BN 256
#define BK 64

typedef __bf16 bf16_t;
typedef __attribute__((ext_vector_type(8))) __bf16 bf16x8;
typedef __attribute__((ext_vector_type(4))) __bf16 bf16x4;
typedef __attribute__((ext_vector_type(4))) float f32x4;

__device__ __forceinline__ float q16(float x) {
    // floor-quantize to 2^-16 steps, clamp to [-2^15, 2^15 - 1]
    float f = floorf(x * 65536.0f) * (1.0f / 65536.0f);
    return fminf(fmaxf(f, -32768.0f), 32767.0f);
}

__global__ void quant_input_kernel(const float* __restrict__ in,
                                   bf16_t* __restrict__ out, int nvec) {
    int stride = gridDim.x * blockDim.x;
    for (int i = blockIdx.x * blockDim.x + threadIdx.x; i < nvec; i += stride) {
        float4 v = reinterpret_cast<const float4*>(in)[i];
        bf16x4 o;
        o[0] = (bf16_t)q16(v.x);
        o[1] = (bf16_t)q16(v.y);
        o[2] = (bf16_t)q16(v.z);
        o[3] = (bf16_t)q16(v.w);
        reinterpret_cast<bf16x4*>(out)[i] = o;
    }
}

__global__ void make_weight_kernel(const float* __restrict__ shift,
                                   const float* __restrict__ sign_,
                                   bf16_t* __restrict__ out, int nvec) {
    int stride = gridDim.x * blockDim.x;
    for (int i = blockIdx.x * blockDim.x + threadIdx.x; i < nvec; i += stride) {
        float4 sh = reinterpret_cast<const float4*>(shift)[i];
        float4 sg = reinterpret_cast<const float4*>(sign_)[i];
        float shs[4] = {sh.x, sh.y, sh.z, sh.w};
        float sgs[4] = {sg.x, sg.y, sg.z, sg.w};
        bf16x4 o;
#pragma unroll
        for (int j = 0; j < 4; ++j) {
            float s = fminf(fmaxf(sgs[j], -1.0f), 1.0f);
            float sv = (s > 0.0f) ? 1.0f : ((s < 0.0f) ? -1.0f : 0.0f);
            o[j] = (bf16_t)(exp2f(rintf(shs[j])) * sv);
        }
        reinterpret_cast<bf16x4*>(out)[i] = o;
    }
}

// ---- 256x256 8-phase bf16 GEMM: C[M][N] = A[M][K]*B[N][K]^T + q16(bias)[N]

// stage one 64-row chunk pair (128 rows x 64 cols = one half-tile, 2 loads/thread)
#define STAGE(LDSOFF, SRC) do {                                                          \
    const bf16_t* _s = (SRC);                                                            \
    bf16_t* _d = &lds[(LDSOFF)] + tid * 8;                                               \
    __builtin_amdgcn_global_load_lds((const __attribute__((address_space(1))) void*)_s,  \
                                     (__attribute__((address_space(3))) void*)_d,        \
                                     16, 0, 0);                                          \
    __builtin_amdgcn_global_load_lds(                                                    \
        (const __attribute__((address_space(1))) void*)(_s + (size_t)64 * K),            \
        (__attribute__((address_space(3))) void*)(_d + 4096), 16, 0, 0);                 \
} while (0)

// read A fragments for quadrant row-half MH (8 x ds_read_b128, swizzled)
#define READ_A(BUF, MH) do {                                                             \
    const bf16_t* _As = &lds[(BUF) * 32768 + wm * 8192];                                 \
    _Pragma("unroll") for (int m = 0; m < 4; ++m)                                        \
        _Pragma("unroll") for (int kk = 0; kk < 2; ++kk)                                 \
            af[m][kk] = *(const bf16x8*)&_As[((MH) * 64 + m * 16 + fr) * 64 +            \
                                             ((((kk << 2) | hi) ^ fr7) << 3)];           \
} while (0)

// read B fragments for quadrant col-half NH (4 x ds_read_b128, swizzled)
#define READ_B(BUF, NH, BF) do {                                                         \
    const bf16_t* _Bs = &lds[(BUF) * 32768 + 16384 + (wn >> 1) * 8192];                  \
    _Pragma("unroll") for (int n = 0; n < 2; ++n)                                        \
        _Pragma("unroll") for (int kk = 0; kk < 2; ++kk)                                 \
            BF[n][kk] = *(const bf16x8*)&_Bs[((wn & 1) * 64 + ((NH) * 2 + n) * 16 + fr)  \
                                                 * 64 +                                  \
                                             ((((kk << 2) | hi) ^ fr7) << 3)];           \
} while (0)

// 16 MFMA = one C-quadrant x K=64
#define QUAD(MH, NH, BF) do {                                                            \
    _Pragma("unroll") for (int m = 0; m < 4; ++m)                                        \
        _Pragma("unroll") for (int n = 0; n < 2; ++n)                                    \
            _Pragma("unroll") for (int kk = 0; kk < 2; ++kk)                             \
                acc[(MH) * 4 + m][(NH) * 2 + n] =                                        \
                    __builtin_amdgcn_mfma_f32_16x16x32_bf16(                             \
                        af[m][kk], BF[n][kk], acc[(MH) * 4 + m][(NH) * 2 + n], 0, 0, 0); \
} while (0)

#define PH_SYNC_MFMA(MH, NH, BF)                                                         \
    __builtin_amdgcn_s_barrier();                                                        \
    asm volatile("s_waitcnt lgkmcnt(0)" ::: "memory");                                   \
    __builtin_amdgcn_sched_barrier(0);                                                   \
    __builtin_amdgcn_s_setprio(1);                                                       \
    QUAD(MH, NH, BF);                                                                    \
    __builtin_amdgcn_s_setprio(0);

// one K-tile = 4 phases. Staging schedule (3+ phases ahead of consumption):
//   .0: B-half1 of t+1   .1: A-half1 of t+1   .2: B-half0 of t+2   .3: A-half0 of t+2
// slot WAR safety: B slots last read at .1, A slots at .2 (quadrant order 00,01,10,11)
#define TILE(BUF, T, S01, S23, ENDW) do {                                                \
    /* phase 0: quad(0,0) */                                                             \
    READ_A(BUF, 0);                                                                      \
    READ_B(BUF, 0, b0f);                                                                 \
    if (S01) STAGE(((BUF) ^ 1) * 32768 + 3 * 8192, srcB1 + (size_t)((T) + 1) * 64);      \
    PH_SYNC_MFMA(0, 0, b0f)                                                              \
    __builtin_amdgcn_s_barrier(); __builtin_amdgcn_sched_barrier(0);                     \
    /* phase 1: quad(0,1) */                                                             \
    READ_B(BUF, 1, b1f);                                                                 \
    if (S01) STAGE(((BUF) ^ 1) * 32768 + 1 * 8192, srcA1 + (size_t)((T) + 1) * 64);      \
    PH_SYNC_MFMA(0, 1, b1f)                                                              \
    __builtin_amdgcn_s_barrier(); __builtin_amdgcn_sched_barrier(0);                     \
    /* phase 2: quad(1,0) */                                                             \
    READ_A(BUF, 1);                                                                      \
    if (S23) STAGE((BUF) * 32768 + 2 * 8192, srcB0 + (size_t)((T) + 2) * 64);            \
    PH_SYNC_MFMA(1, 0, b0f)                                                              \
    __builtin_amdgcn_s_barrier(); __builtin_amdgcn_sched_barrier(0);                     \
    /* phase 3: quad(1,1) + tile-boundary counted vmcnt */                               \
    if (S23) STAGE((BUF) * 32768 + 0 * 8192, srcA0 + (size_t)((T) + 2) * 64);            \
    PH_SYNC_MFMA(1, 1, b1f)                                                              \
    if ((ENDW) == 4) asm volatile("s_waitcnt vmcnt(4)" ::: "memory");                    \
    if ((ENDW) == 0) asm volatile("s_waitcnt vmcnt(0)" ::: "memory");                    \
    __builtin_amdgcn_s_barrier(); __builtin_amdgcn_sched_barrier(0);                     \
} while (0)

__global__ __launch_bounds__(512, 2)
void gemm256_kernel(const bf16_t* __restrict__ A,
                    const bf16_t* __restrict__ B,
                    const float* __restrict__ bias,
                    float* __restrict__ C,
                    int M, int N, int K) {
    // 128 KiB: buf{0,1} x slots {A0,A1,B0,B1} x 8192 bf16 (128 rows x 64 cols)
    __shared__ bf16_t lds[65536];

    const int ntn = N / BN;
    const int nwg = gridDim.x;
    // bijective XCD swizzle (8 XCDs)
    const int q = nwg >> 3, r = nwg & 7;
    const int xcd = blockIdx.x & 7, lid = blockIdx.x >> 3;
    const int swz = (xcd < r ? xcd * (q + 1) : r * (q + 1) + (xcd - r) * q) + lid;
    const int tile_m = (swz / ntn) * BM;
    const int tile_n = (swz % ntn) * BN;

    const int tid = threadIdx.x;
    const int lane = tid & 63;
    const int wid = tid >> 6;
    const int wm = wid >> 2;   // 0..1: row half
    const int wn = wid & 3;    // 0..3: col quarter
    const int fr = lane & 15;
    const int hi = lane >> 4;
    const int fr7 = fr & 7;

    // inverse-swizzled global source column (bytes 4-6 ^= row bits 0-2; row=tid>>3)
    const int colsrc_e = ((((tid & 7) * 16) ^ ((tid & 56) << 1)) >> 1);
    const bf16_t* srcA0 = A + (size_t)(tile_m + (tid >> 3)) * K + colsrc_e;
    const bf16_t* srcA1 = srcA0 + (size_t)128 * K;
    const bf16_t* srcB0 = B + (size_t)(tile_n + (tid >> 3)) * K + colsrc_e;
    const bf16_t* srcB1 = srcB0 + (size_t)128 * K;

    bf16x8 af[4][2], b0f[2][2], b1f[2][2];
    f32x4 acc[8][4] = {};

    // prologue: tile0 fully + tile1 first two halves; keep newest 4 loads in flight
    STAGE(16384, srcB0);            // buf0 B0  (tile 0)
    STAGE(0, srcA0);                // buf0 A0
    STAGE(24576, srcB1);            // buf0 B1
    STAGE(8192, srcA1);             // buf0 A1
    STAGE(32768 + 16384, srcB0 + 64);  // buf1 B0 (tile 1)
    STAGE(32768 + 0, srcA0 + 64);      // buf1 A0
    asm volatile("s_waitcnt vmcnt(4)" ::: "memory");
    __builtin_amdgcn_s_barrier();
    __builtin_amdgcn_sched_barrier(0);

    const int npairs = K / 128;   // K-tile pairs (BK=64, 2 tiles/iter)
    for (int i = 0; i < npairs - 1; ++i) {
        TILE(0, 2 * i, 1, 1, 4);
        TILE(1, 2 * i + 1, 1, 1, 4);
    }
    // epilogue pair: finish staging tile NT-1, drain once, compute last two tiles
    TILE(0, 2 * npairs - 2, 1, 0, 0);
    TILE(1, 2 * npairs - 1, 0, 0, -1);

    // epilogue: C/D layout col=lane&15, row=(lane>>4)*4+reg
    float qb[4];
#pragma unroll
    for (int ng = 0; ng < 4; ++ng)
        qb[ng] = q16(bias[tile_n + wn * 64 + ng * 16 + fr]);
#pragma unroll
    for (int mg = 0; mg < 8; ++mg) {
        const int grow0 = tile_m + wm * 128 + mg * 16 + hi * 4;
#pragma unroll
        for (int ng = 0; ng < 4; ++ng) {
            const int gcol = tile_n + wn * 64 + ng * 16 + fr;
#pragma unroll
            for (int rr = 0; rr < 4; ++rr)
                C[(size_t)(grow0 + rr) * N + gcol] = acc[mg][ng][rr] + qb[ng];
        }
    }
}

extern "C" void kernel_launch(void* const* d_in, const int* in_sizes, int n_in,
                              void* d_out, int out_size, void* d_ws, size_t ws_size,
                              hipStream_t stream) {
    const float* inp   = (const float*)d_in[0];
    const float* shift = (const float*)d_in[1];
    const float* sign_ = (const float*)d_in[2];
    const float* bias  = (const float*)d_in[3];
    float* out = (float*)d_out;

    const int OUT_F = in_sizes[3];              // 4096
    const int IN_F  = in_sizes[1] / OUT_F;      // 4096
    const int Mrows = in_sizes[0] / IN_F;       // 4096

    bf16_t* Aq = (bf16_t*)d_ws;
    bf16_t* Wq = Aq + (size_t)Mrows * IN_F;     // (M*K + N*K)*2 = 67.2 MB of ws

    const int nA = Mrows * IN_F;
    const int nW = OUT_F * IN_F;

    quant_input_kernel<<<2048, 256, 0, stream>>>(inp, Aq, nA >> 2);
    make_weight_kernel<<<2048, 256, 0, stream>>>(shift, sign_, Wq, nW >> 2);

    dim3 grid((Mrows / BM) * (OUT_F / BN));
    gemm256_kernel<<<grid, 512, 0, stream>>>(Aq, Wq, bias, out,
                                             Mrows, OUT_F, IN_F);
}